// Round 6
// baseline (283.804 us; speedup 1.0000x reference)
//
#include <hip/hip_runtime.h>
#include <hip/hip_cooperative_groups.h>

namespace cg = cooperative_groups;

#define NTOT 768
#define NHALF 384
#define DDIM 64
#define NPER 200
#define PPAD 256
#define NKER 4
#define CHUNK 192
#define NMB 12      // m-blocks of 64 rows
#define NBLK 256    // cooperative grid size
#define NB_GEMM 192 // 12 mb * 4 nc * 4 k
#define NA_UNITS (NPER + NTOT)

typedef __attribute__((ext_vector_type(8))) short short8;    // 8 bf16 (4 VGPR)
typedef __attribute__((ext_vector_type(4))) float floatx4;   // MFMA acc

constexpr int K0SZ  = NTOT * NTOT;
constexpr int OF_KH = 0;                                  // bf16 K [4][768][768] (ushort)
constexpr int KH_FLOATS = NKER * K0SZ / 2;
constexpr int OF_RS0 = OF_KH + KH_FLOATS;
constexpr int OF_RSX = OF_RS0 + NKER * NTOT;
constexpr int OF_RSY = OF_RSX + NKER * NTOT;
constexpr int OF_C   = OF_RSY + NKER * NTOT;
constexpr int OF_ROWM = OF_C + NKER * NHALF;
constexpr int OF_COLM = OF_ROWM + NKER * NTOT;
constexpr int OF_SCAL = OF_COLM + NKER * NTOT;
constexpr int OF_STT  = OF_SCAL + 16;                     // bf16 S^T [PPAD][NTOT]
constexpr int STT_FLOATS = PPAD * NTOT / 2;
constexpr int OF_Q0P  = OF_STT + STT_FLOATS;              // fp32 [4][NMB][PPAD] partials

// shared scratch: zb[CHUNK*65] + zaS[64] + redw[32] = 12576 floats = 50304 B (< 64 KiB)
constexpr int SMEMF = CHUNK * 65 + DDIM + 32;

__device__ __forceinline__ unsigned short f2bf(float f) {  // RTN
    unsigned int u = __float_as_uint(f);
    return (unsigned short)((u + 0x7FFFu + ((u >> 16) & 1u)) >> 16);
}
__device__ __forceinline__ float bf2f(unsigned short h) {
    return __uint_as_float(((unsigned int)h) << 16);
}

// ================= phase A unit: scatter (u<NPER) or K-row build =================
__device__ __forceinline__ void phaseA_unit(int u, const float* __restrict__ X,
                                            const float* __restrict__ Y,
                                            const int* __restrict__ perms,
                                            const float* ib2, const float* ib1,
                                            float* __restrict__ ws, float* smem) {
    int tid = threadIdx.x, wave = tid >> 6, lane = tid & 63;
    float* zb  = smem;
    float* zaS = smem + CHUNK * 65;
    float* redw = smem + CHUNK * 65 + DDIM;
    unsigned short* STT = (unsigned short*)(ws + OF_STT);
    unsigned short* KH  = (unsigned short*)(ws + OF_KH);
    __syncthreads();   // protect smem reuse across units

    if (u < NPER) {
        if (tid < 192) {
            ((uint2*)(STT + u * NTOT))[tid] = make_uint2(0u, 0u);
            if (u < PPAD - NPER)
                ((uint2*)(STT + (NPER + u) * NTOT))[tid] = make_uint2(0u, 0u);
        }
        __syncthreads();
        int v = perms[u * NTOT + tid];
        STT[u * NTOT + v] = 0x3F80;  // bf16 1.0
        if (tid < NHALF - 256) {
            int v2 = perms[u * NTOT + 256 + tid];
            STT[u * NTOT + v2] = 0x3F80;
        }
        return;
    }

    int a = u - NPER;
    const float* za = (a < NHALF) ? X + a * DDIM : Y + (a - NHALF) * DDIM;
    if (tid < DDIM) zaS[tid] = za[tid];
    __syncthreads();
    float sqa = 0.f;
#pragma unroll
    for (int d = 0; d < DDIM; ++d) sqa = fmaf(zaS[d], zaS[d], sqa);
    float accX[NKER] = {0.f, 0.f, 0.f, 0.f};
    float accY[NKER] = {0.f, 0.f, 0.f, 0.f};

    for (int c0 = 0; c0 < NTOT; c0 += CHUNK) {
        __syncthreads();
        for (int idx = tid; idx < CHUNK * DDIM; idx += 256) {
            int r = idx >> 6, d = idx & 63;
            int gr = c0 + r;
            const float* zr = (gr < NHALF) ? X + gr * DDIM : Y + (gr - NHALF) * DDIM;
            zb[r * 65 + d] = zr[d];
        }
        __syncthreads();
        if (tid < CHUNK) {
            int b = c0 + tid;
            float dot = 0.f, sqb = 0.f;
#pragma unroll
            for (int d = 0; d < DDIM; ++d) {
                float zv = zb[tid * 65 + d];
                dot = fmaf(zaS[d], zv, dot);
                sqb = fmaf(zv, zv, sqb);
            }
            float d2 = (sqa + sqb) - 2.f * dot;
            if (b == a) d2 = 0.f;
            d2 = fmaxf(d2, 0.f);
            float d2e = d2 + 1e-12f;
            float dist = sqrtf(d2e);
#pragma unroll
            for (int k = 0; k < NKER; ++k) {
                float val = ((k & 1) == 0) ? __expf(-d2e * ib2[k]) : __expf(-dist * ib1[k]);
                KH[k * K0SZ + a * NTOT + b] = f2bf(val);
                if (b < NHALF) accX[k] += val; else accY[k] += val;
                if (a < NHALF && b == a + NHALF) ws[OF_C + k * NHALF + a] = val;
            }
        }
    }
    float vals[8];
#pragma unroll
    for (int k = 0; k < NKER; ++k) { vals[k] = accX[k]; vals[4 + k] = accY[k]; }
#pragma unroll
    for (int off = 32; off > 0; off >>= 1)
#pragma unroll
        for (int v = 0; v < 8; ++v) vals[v] += __shfl_down(vals[v], off, 64);
    __syncthreads();
    if (lane == 0)
#pragma unroll
        for (int v = 0; v < 8; ++v) redw[wave * 8 + v] = vals[v];
    __syncthreads();
    if (tid == 0) {
#pragma unroll
        for (int k = 0; k < NKER; ++k) {
            float sx = redw[k] + redw[8 + k] + redw[16 + k] + redw[24 + k];
            float sy = redw[4 + k] + redw[12 + k] + redw[20 + k] + redw[28 + k];
            ws[OF_RS0 + k * NTOT + a] = sx + sy;
            ws[OF_RSX + k * NTOT + a] = sx;
            ws[OF_RSY + k * NTOT + a] = sy;
        }
    }
}

// ================= phase B gemm unit: 64 m-rows x 64 perms, one k =================
__device__ __forceinline__ void phaseB_gemm(int unit, float* __restrict__ ws, float* smem) {
    int tid = threadIdx.x, wave = tid >> 6, lane = tid & 63;
    int mb = unit % NMB;
    int t  = unit / NMB;
    int nc = t & 3;
    int k  = t >> 2;
    int m0 = mb * 64 + wave * 16;
    int n0 = nc * 64;
    int row = lane & 15, quad = lane >> 4;
    const unsigned short* KH  = (const unsigned short*)(ws + OF_KH);
    const unsigned short* STT = (const unsigned short*)(ws + OF_STT);
    const unsigned short* aptr = KH + k * K0SZ + (m0 + row) * NTOT + quad * 8;
    floatx4 acc[4][2];
#pragma unroll
    for (int j = 0; j < 4; ++j)
#pragma unroll
        for (int h = 0; h < 2; ++h) acc[j][h] = (floatx4){0.f, 0.f, 0.f, 0.f};
    for (int kk = 0; kk < NTOT; kk += 64) {
        short8 a0 = *(const short8*)(aptr + kk);
        short8 a1 = *(const short8*)(aptr + kk + 32);
#pragma unroll
        for (int j = 0; j < 4; ++j) {
            const unsigned short* bp = STT + (n0 + j * 16 + row) * NTOT + quad * 8 + kk;
            short8 b0 = *(const short8*)(bp);
            short8 b1 = *(const short8*)(bp + 32);
            acc[j][0] = __builtin_amdgcn_mfma_f32_16x16x32_bf16(a0, b0, acc[j][0], 0, 0, 0);
            acc[j][1] = __builtin_amdgcn_mfma_f32_16x16x32_bf16(a1, b1, acc[j][1], 0, 0, 0);
        }
    }
    __syncthreads();
#pragma unroll
    for (int j = 0; j < 4; ++j) {
        const unsigned short* sp = STT + (n0 + j * 16 + row) * NTOT + m0 + quad * 4;
        float p = 0.f;
#pragma unroll
        for (int r = 0; r < 4; ++r) p += (acc[j][0][r] + acc[j][1][r]) * bf2f(sp[r]);
        p += __shfl_down(p, 32, 64);
        p += __shfl_down(p, 16, 64);
        if (lane < 16) smem[wave * 64 + j * 16 + lane] = p;
    }
    __syncthreads();
    if (tid < 64) {
        float s = smem[tid] + smem[64 + tid] + smem[128 + tid] + smem[192 + tid];
        ws[OF_Q0P + (k * NMB + mb) * PPAD + n0 + tid] = s;
    }
}

// ================= phase B final: totals + U + rowM/colM for one k =================
__device__ __forceinline__ void phaseB_final(int k, const float* __restrict__ bw,
                                             float* __restrict__ ws, float* __restrict__ out,
                                             float* smem) {
    int tid = threadIdx.x, wave = tid >> 6, lane = tid & 63;
    float v[5] = {0.f, 0.f, 0.f, 0.f, 0.f};
    for (int a = tid; a < NTOT; a += 256) v[0] += ws[OF_RS0 + k * NTOT + a];
    for (int a = tid; a < NHALF; a += 256) {
        v[1] += ws[OF_C + k * NHALF + a];
        v[2] += ws[OF_RSX + k * NTOT + a];
        v[3] += ws[OF_RSY + k * NTOT + NHALF + a];
        v[4] += ws[OF_RSY + k * NTOT + a];
    }
#pragma unroll
    for (int off = 32; off > 0; off >>= 1)
#pragma unroll
        for (int j = 0; j < 5; ++j) v[j] += __shfl_down(v[j], off, 64);
    __syncthreads();
    if (lane == 0)
#pragma unroll
        for (int j = 0; j < 5; ++j) smem[wave * 8 + j] = v[j];
    __syncthreads();
    if (tid == 0) {
        float tot0 = smem[0] + smem[8] + smem[16] + smem[24];
        float csum = smem[1] + smem[9] + smem[17] + smem[25];
        float sxx  = smem[2] + smem[10] + smem[18] + smem[26];
        float syy  = smem[3] + smem[11] + smem[19] + smem[27];
        float sxy  = smem[4] + smem[12] + smem[20] + smem[28];
        float b = bw[k];
        float dist0 = sqrtf(1e-12f);
        float dk = ((k & 1) == 0) ? expf(-(dist0 * dist0) / (b * b)) : expf(-dist0 / b);
        ws[OF_SCAL + k * 4 + 0] = tot0 - csum;
        ws[OF_SCAL + k * 4 + 1] = dk;
        double U = ((double)sxx - 384.0 * (double)dk) * (1.0 / 147072.0)
                 + ((double)syy - 384.0 * (double)dk) * (1.0 / 147072.0)
                 - 2.0 * ((double)sxy - (double)csum) * (1.0 / 147456.0);
        out[k * 201] = (float)U;
    }
    for (int idx = tid; idx < NTOT; idx += 256) {
        float r0 = ws[OF_RS0 + k * NTOT + idx];
        float cx = (idx < NHALF)  ? ws[OF_C + k * NHALF + idx] : 0.f;
        float cy = (idx >= NHALF) ? ws[OF_C + k * NHALF + idx - NHALF] : 0.f;
        ws[OF_ROWM + k * NTOT + idx] = r0 - cx;
        ws[OF_COLM + k * NTOT + idx] = r0 - cy;
    }
}

// ================= phase C unit: one permutation, 256 threads =================
__device__ __forceinline__ void phaseC_unit(int p, const int* __restrict__ perms,
                                            const float* __restrict__ ws,
                                            float* __restrict__ out, float* smem) {
    int tid = threadIdx.x, wave = tid >> 6, lane = tid & 63;
    const unsigned short* STT = (const unsigned short*)(ws + OF_STT);
    const unsigned short* KH  = (const unsigned short*)(ws + OF_KH);
    float v[16] = {0.f};  // [k][rs, cs, pair, qc]
    for (int i = tid; i < NHALF; i += 256) {
        int a  = perms[p * NTOT + i];
        int bY = perms[p * NTOT + NHALF + i];
        float si  = bf2f(STT[p * NTOT + i]);
        float si2 = bf2f(STT[p * NTOT + NHALF + i]);
#pragma unroll
        for (int k = 0; k < NKER; ++k) {
            v[k * 4 + 0] += ws[OF_ROWM + k * NTOT + a];
            v[k * 4 + 1] += ws[OF_COLM + k * NTOT + a];
            float kv = bf2f(KH[k * K0SZ + a * NTOT + bY]);
            if (a < NHALF && bY == a + NHALF) kv = 0.f;
            v[k * 4 + 2] += kv;
            v[k * 4 + 3] += ws[OF_C + k * NHALF + i] * si * si2;
        }
    }
#pragma unroll
    for (int off = 32; off > 0; off >>= 1)
#pragma unroll
        for (int j = 0; j < 16; ++j) v[j] += __shfl_down(v[j], off, 64);
    __syncthreads();
    if (lane == 0)
#pragma unroll
        for (int j = 0; j < 16; ++j) smem[wave * 16 + j] = v[j];
    __syncthreads();
    if (tid < 16) smem[64 + tid] = smem[tid] + smem[16 + tid] + smem[32 + tid] + smem[48 + tid];
    __syncthreads();
    if (tid < NKER) {
        int k = tid;
        double rs = smem[64 + k * 4 + 0], cs = smem[64 + k * 4 + 1];
        double pair = smem[64 + k * 4 + 2], qc = smem[64 + k * 4 + 3];
        double total_mod = (double)ws[OF_SCAL + k * 4 + 0];
        double dk        = (double)ws[OF_SCAL + k * 4 + 1];
        double q = -qc;
#pragma unroll
        for (int mb = 0; mb < NMB; ++mb) q += (double)ws[OF_Q0P + (k * NMB + mb) * PPAD + p];
        double sXX = q - 384.0 * dk;
        double sYY = total_mod - rs - cs + q - 384.0 * dk;
        double sXY = rs - q - pair;
        out[k * 201 + 1 + p] =
            (float)(sXX * (1.0 / 147072.0) + sYY * (1.0 / 147072.0) - 2.0 * sXY * (1.0 / 147456.0));
    }
}

// ===================== cooperative mega-kernel =====================
__global__ __launch_bounds__(256) void k_mega(const float* __restrict__ X,
                                              const float* __restrict__ Y,
                                              const float* __restrict__ bw,
                                              const int* __restrict__ perms,
                                              float* __restrict__ ws,
                                              float* __restrict__ out) {
    __shared__ float smem[SMEMF];
    cg::grid_group grid = cg::this_grid();
    float ib2[NKER], ib1[NKER];
#pragma unroll
    for (int k = 0; k < NKER; ++k) { float b = bw[k]; ib2[k] = 1.f / (b * b); ib1[k] = 1.f / b; }

    for (int u = blockIdx.x; u < NA_UNITS; u += NBLK)
        phaseA_unit(u, X, Y, perms, ib2, ib1, ws, smem);

    __threadfence();
    grid.sync();

    if (blockIdx.x < NB_GEMM)           phaseB_gemm(blockIdx.x, ws, smem);
    else if (blockIdx.x < NB_GEMM + NKER) phaseB_final(blockIdx.x - NB_GEMM, bw, ws, out, smem);

    __threadfence();
    grid.sync();

    if (blockIdx.x < NPER) phaseC_unit(blockIdx.x, perms, ws, out, smem);
}

// ===================== fallback standalone kernels (same math) =====================
__global__ __launch_bounds__(256) void k_s1(const float* __restrict__ X,
                                            const float* __restrict__ Y,
                                            const float* __restrict__ bw,
                                            const int* __restrict__ perms,
                                            float* __restrict__ ws) {
    __shared__ float smem[SMEMF];
    float ib2[NKER], ib1[NKER];
#pragma unroll
    for (int k = 0; k < NKER; ++k) { float b = bw[k]; ib2[k] = 1.f / (b * b); ib1[k] = 1.f / b; }
    phaseA_unit(blockIdx.x, X, Y, perms, ib2, ib1, ws, smem);
}

__global__ __launch_bounds__(256) void k_s2(const float* __restrict__ bw,
                                            float* __restrict__ ws, float* __restrict__ out) {
    __shared__ float smem[256];
    if (blockIdx.x < NB_GEMM) phaseB_gemm(blockIdx.x, ws, smem);
    else                      phaseB_final(blockIdx.x - NB_GEMM, bw, ws, out, smem);
}

__global__ __launch_bounds__(256) void k_s3(const int* __restrict__ perms,
                                            const float* __restrict__ ws,
                                            float* __restrict__ out) {
    __shared__ float smem[128];
    phaseC_unit(blockIdx.x, perms, ws, out, smem);
}

extern "C" void kernel_launch(void* const* d_in, const int* in_sizes, int n_in,
                              void* d_out, int out_size, void* d_ws, size_t ws_size,
                              hipStream_t stream) {
    const float* X     = (const float*)d_in[0];
    const float* Y     = (const float*)d_in[1];
    const float* bw    = (const float*)d_in[2];
    const int*   perms = (const int*)d_in[3];
    float* ws  = (float*)d_ws;
    float* out = (float*)d_out;

    void* args[] = {(void*)&X, (void*)&Y, (void*)&bw, (void*)&perms, (void*)&ws, (void*)&out};
    hipError_t e = hipLaunchCooperativeKernel((void*)k_mega, dim3(NBLK), dim3(256), args, 0, stream);
    if (e != hipSuccess) {
        (void)hipGetLastError();  // clear sticky error; run equivalent 3-dispatch path
        k_s1<<<NA_UNITS, 256, 0, stream>>>(X, Y, bw, perms, ws);
        k_s2<<<NB_GEMM + NKER, 256, 0, stream>>>(bw, ws, out);
        k_s3<<<NPER, 256, 0, stream>>>(perms, ws, out);
    }
}

// Round 7
// 112.972 us; speedup vs baseline: 2.5122x; 2.5122x over previous
//
#include <hip/hip_runtime.h>

#define NTOT 768
#define NHALF 384
#define DDIM 64
#define NPER 200
#define PPAD 256
#define NKER 4
#define CHUNK 192
#define NMB 12      // m-blocks of 64 rows
#define NB_GEMM 192 // 12 mb * 4 nc * 4 k

typedef __attribute__((ext_vector_type(8))) short short8;    // 8 bf16 (4 VGPR)
typedef __attribute__((ext_vector_type(4))) float floatx4;   // MFMA acc

constexpr int K0SZ  = NTOT * NTOT;
constexpr int OF_KH = 0;                                  // bf16 K [4][768][768] (ushort)
constexpr int KH_FLOATS = NKER * K0SZ / 2;
constexpr int OF_RS0 = OF_KH + KH_FLOATS;
constexpr int OF_RSX = OF_RS0 + NKER * NTOT;
constexpr int OF_RSY = OF_RSX + NKER * NTOT;
constexpr int OF_C   = OF_RSY + NKER * NTOT;
constexpr int OF_ROWM = OF_C + NKER * NHALF;
constexpr int OF_COLM = OF_ROWM + NKER * NTOT;
constexpr int OF_SCAL = OF_COLM + NKER * NTOT;
constexpr int OF_STT  = OF_SCAL + 16;                     // bf16 S^T [PPAD][NTOT]
constexpr int STT_FLOATS = PPAD * NTOT / 2;
constexpr int OF_Q0P  = OF_STT + STT_FLOATS;              // fp32 [4][NMB][PPAD] partials

// smem: zb[CHUNK*65] + zaS[128] + redw[64] = 12672 floats = 50688 B (3 blocks/CU)
constexpr int SMEMF = CHUNK * 65 + 2 * DDIM + 64;

__device__ __forceinline__ unsigned short f2bf(float f) {  // RTN
    unsigned int u = __float_as_uint(f);
    return (unsigned short)((u + 0x7FFFu + ((u >> 16) & 1u)) >> 16);
}
__device__ __forceinline__ float bf2f(unsigned short h) {
    return __uint_as_float(((unsigned int)h) << 16);
}

// ============ stage 1: scatter STT (bid<200) or 2-row K build (rows a0, a0+384) ============
__global__ __launch_bounds__(256) void k_s1(const float* __restrict__ X,
                                            const float* __restrict__ Y,
                                            const float* __restrict__ bw,
                                            const int* __restrict__ perms,
                                            float* __restrict__ ws) {
    __shared__ float smem[SMEMF];
    float* zb   = smem;
    float* zaS  = smem + CHUNK * 65;        // 128: rows a0 (X) and a0+384 (Y)
    float* redw = zaS + 2 * DDIM;           // 64
    int bid = blockIdx.x, tid = threadIdx.x;
    int wave = tid >> 6, lane = tid & 63;
    unsigned short* STT = (unsigned short*)(ws + OF_STT);
    unsigned short* KH  = (unsigned short*)(ws + OF_KH);

    if (bid < NPER) {
        if (tid < 192) {
            ((uint2*)(STT + bid * NTOT))[tid] = make_uint2(0u, 0u);
            if (bid < PPAD - NPER)
                ((uint2*)(STT + (NPER + bid) * NTOT))[tid] = make_uint2(0u, 0u);
        }
        __syncthreads();
        int v = perms[bid * NTOT + tid];
        STT[bid * NTOT + v] = 0x3F80;  // bf16 1.0
        if (tid < NHALF - 256) {
            int v2 = perms[bid * NTOT + 256 + tid];
            STT[bid * NTOT + v2] = 0x3F80;
        }
        return;
    }

    int a0 = bid - NPER;        // X row
    int a1 = a0 + NHALF;        // Y row (same index into Y)
    if (tid < DDIM)               zaS[tid] = X[a0 * DDIM + tid];
    else if (tid < 2 * DDIM)      zaS[tid] = Y[a0 * DDIM + (tid - DDIM)];
    float ib2[NKER], ib1[NKER];
#pragma unroll
    for (int k = 0; k < NKER; ++k) { float b = bw[k]; ib2[k] = 1.f / (b * b); ib1[k] = 1.f / b; }
    __syncthreads();
    float sq0 = 0.f, sq1 = 0.f;
#pragma unroll
    for (int d = 0; d < DDIM; ++d) {
        sq0 = fmaf(zaS[d], zaS[d], sq0);
        sq1 = fmaf(zaS[DDIM + d], zaS[DDIM + d], sq1);
    }
    float acc[16];   // [row(2)][XY(2)][k(4)]
#pragma unroll
    for (int j = 0; j < 16; ++j) acc[j] = 0.f;

    for (int c0 = 0; c0 < NTOT; c0 += CHUNK) {
        __syncthreads();
        for (int idx = tid; idx < CHUNK * DDIM; idx += 256) {
            int r = idx >> 6, d = idx & 63;
            int gr = c0 + r;
            const float* zr = (gr < NHALF) ? X + gr * DDIM : Y + (gr - NHALF) * DDIM;
            zb[r * 65 + d] = zr[d];
        }
        __syncthreads();
        if (tid < CHUNK) {
            int b = c0 + tid;
            float dot0 = 0.f, dot1 = 0.f, sqb = 0.f;
#pragma unroll
            for (int d = 0; d < DDIM; ++d) {
                float zv = zb[tid * 65 + d];
                dot0 = fmaf(zaS[d], zv, dot0);
                dot1 = fmaf(zaS[DDIM + d], zv, dot1);
                sqb  = fmaf(zv, zv, sqb);
            }
            // row a0
            {
                float d2 = (sq0 + sqb) - 2.f * dot0;
                if (b == a0) d2 = 0.f;
                d2 = fmaxf(d2, 0.f);
                float d2e = d2 + 1e-12f;
                float dist = sqrtf(d2e);
#pragma unroll
                for (int k = 0; k < NKER; ++k) {
                    float val = ((k & 1) == 0) ? __expf(-d2e * ib2[k]) : __expf(-dist * ib1[k]);
                    KH[k * K0SZ + a0 * NTOT + b] = f2bf(val);
                    if (b < NHALF) acc[k] += val; else acc[4 + k] += val;
                    if (b == a0 + NHALF) ws[OF_C + k * NHALF + a0] = val;
                }
            }
            // row a1
            {
                float d2 = (sq1 + sqb) - 2.f * dot1;
                if (b == a1) d2 = 0.f;
                d2 = fmaxf(d2, 0.f);
                float d2e = d2 + 1e-12f;
                float dist = sqrtf(d2e);
#pragma unroll
                for (int k = 0; k < NKER; ++k) {
                    float val = ((k & 1) == 0) ? __expf(-d2e * ib2[k]) : __expf(-dist * ib1[k]);
                    KH[k * K0SZ + a1 * NTOT + b] = f2bf(val);
                    if (b < NHALF) acc[8 + k] += val; else acc[12 + k] += val;
                }
            }
        }
    }
#pragma unroll
    for (int off = 32; off > 0; off >>= 1)
#pragma unroll
        for (int j = 0; j < 16; ++j) acc[j] += __shfl_down(acc[j], off, 64);
    __syncthreads();
    if (lane == 0)
#pragma unroll
        for (int j = 0; j < 16; ++j) redw[wave * 16 + j] = acc[j];
    __syncthreads();
    if (tid == 0) {
#pragma unroll
        for (int k = 0; k < NKER; ++k) {
            float sx0 = redw[k]      + redw[16 + k]      + redw[32 + k]      + redw[48 + k];
            float sy0 = redw[4 + k]  + redw[20 + k]      + redw[36 + k]      + redw[52 + k];
            float sx1 = redw[8 + k]  + redw[24 + k]      + redw[40 + k]      + redw[56 + k];
            float sy1 = redw[12 + k] + redw[28 + k]      + redw[44 + k]      + redw[60 + k];
            ws[OF_RS0 + k * NTOT + a0] = sx0 + sy0;
            ws[OF_RSX + k * NTOT + a0] = sx0;
            ws[OF_RSY + k * NTOT + a0] = sy0;
            ws[OF_RS0 + k * NTOT + a1] = sx1 + sy1;
            ws[OF_RSX + k * NTOT + a1] = sx1;
            ws[OF_RSY + k * NTOT + a1] = sy1;
        }
    }
}

// ============ stage 2: gemm (bid<192, 64 m-rows x 64 perms) or final (k=bid-192) ============
__global__ __launch_bounds__(256) void k_s2(const float* __restrict__ bw,
                                            float* __restrict__ ws, float* __restrict__ out) {
    __shared__ float smem[256];
    int bid = blockIdx.x, tid = threadIdx.x;
    int wave = tid >> 6, lane = tid & 63;

    if (bid < NB_GEMM) {
        int mb = bid % NMB;
        int t  = bid / NMB;
        int nc = t & 3;
        int k  = t >> 2;
        int m0 = mb * 64 + wave * 16;
        int n0 = nc * 64;
        int row = lane & 15, quad = lane >> 4;
        const unsigned short* KH  = (const unsigned short*)(ws + OF_KH);
        const unsigned short* STT = (const unsigned short*)(ws + OF_STT);
        const unsigned short* aptr = KH + k * K0SZ + (m0 + row) * NTOT + quad * 8;
        floatx4 acc[4][2];
#pragma unroll
        for (int j = 0; j < 4; ++j)
#pragma unroll
            for (int h = 0; h < 2; ++h) acc[j][h] = (floatx4){0.f, 0.f, 0.f, 0.f};
        for (int kk = 0; kk < NTOT; kk += 64) {
            short8 a0 = *(const short8*)(aptr + kk);
            short8 a1 = *(const short8*)(aptr + kk + 32);
#pragma unroll
            for (int j = 0; j < 4; ++j) {
                const unsigned short* bp = STT + (n0 + j * 16 + row) * NTOT + quad * 8 + kk;
                short8 b0 = *(const short8*)(bp);
                short8 b1 = *(const short8*)(bp + 32);
                acc[j][0] = __builtin_amdgcn_mfma_f32_16x16x32_bf16(a0, b0, acc[j][0], 0, 0, 0);
                acc[j][1] = __builtin_amdgcn_mfma_f32_16x16x32_bf16(a1, b1, acc[j][1], 0, 0, 0);
            }
        }
        __syncthreads();
#pragma unroll
        for (int j = 0; j < 4; ++j) {
            const unsigned short* sp = STT + (n0 + j * 16 + row) * NTOT + m0 + quad * 4;
            float p = 0.f;
#pragma unroll
            for (int r = 0; r < 4; ++r) p += (acc[j][0][r] + acc[j][1][r]) * bf2f(sp[r]);
            p += __shfl_down(p, 32, 64);
            p += __shfl_down(p, 16, 64);
            if (lane < 16) smem[wave * 64 + j * 16 + lane] = p;
        }
        __syncthreads();
        if (tid < 64) {
            float s = smem[tid] + smem[64 + tid] + smem[128 + tid] + smem[192 + tid];
            ws[OF_Q0P + (k * NMB + mb) * PPAD + n0 + tid] = s;
        }
        return;
    }

    int k = bid - NB_GEMM;
    float v[5] = {0.f, 0.f, 0.f, 0.f, 0.f};
    for (int a = tid; a < NTOT; a += 256) v[0] += ws[OF_RS0 + k * NTOT + a];
    for (int a = tid; a < NHALF; a += 256) {
        v[1] += ws[OF_C + k * NHALF + a];
        v[2] += ws[OF_RSX + k * NTOT + a];
        v[3] += ws[OF_RSY + k * NTOT + NHALF + a];
        v[4] += ws[OF_RSY + k * NTOT + a];
    }
#pragma unroll
    for (int off = 32; off > 0; off >>= 1)
#pragma unroll
        for (int j = 0; j < 5; ++j) v[j] += __shfl_down(v[j], off, 64);
    __syncthreads();
    if (lane == 0)
#pragma unroll
        for (int j = 0; j < 5; ++j) smem[wave * 8 + j] = v[j];
    __syncthreads();
    if (tid == 0) {
        float tot0 = smem[0] + smem[8] + smem[16] + smem[24];
        float csum = smem[1] + smem[9] + smem[17] + smem[25];
        float sxx  = smem[2] + smem[10] + smem[18] + smem[26];
        float syy  = smem[3] + smem[11] + smem[19] + smem[27];
        float sxy  = smem[4] + smem[12] + smem[20] + smem[28];
        float b = bw[k];
        float dist0 = sqrtf(1e-12f);
        float dk = ((k & 1) == 0) ? expf(-(dist0 * dist0) / (b * b)) : expf(-dist0 / b);
        ws[OF_SCAL + k * 4 + 0] = tot0 - csum;
        ws[OF_SCAL + k * 4 + 1] = dk;
        double U = ((double)sxx - 384.0 * (double)dk) * (1.0 / 147072.0)
                 + ((double)syy - 384.0 * (double)dk) * (1.0 / 147072.0)
                 - 2.0 * ((double)sxy - (double)csum) * (1.0 / 147456.0);
        out[k * 201] = (float)U;
    }
    for (int idx = tid; idx < NTOT; idx += 256) {
        float r0 = ws[OF_RS0 + k * NTOT + idx];
        float cx = (idx < NHALF)  ? ws[OF_C + k * NHALF + idx] : 0.f;
        float cy = (idx >= NHALF) ? ws[OF_C + k * NHALF + idx - NHALF] : 0.f;
        ws[OF_ROWM + k * NTOT + idx] = r0 - cx;
        ws[OF_COLM + k * NTOT + idx] = r0 - cy;
    }
}

// ============ stage 3: per-permutation gathered sums + final U_b ============
__global__ __launch_bounds__(256) void k_s3(const int* __restrict__ perms,
                                            const float* __restrict__ ws,
                                            float* __restrict__ out) {
    __shared__ float smem[128];
    int p = blockIdx.x, tid = threadIdx.x;
    int wave = tid >> 6, lane = tid & 63;
    const unsigned short* STT = (const unsigned short*)(ws + OF_STT);
    const unsigned short* KH  = (const unsigned short*)(ws + OF_KH);
    float v[16] = {0.f};  // [k][rs, cs, pair, qc]
    for (int i = tid; i < NHALF; i += 256) {
        int a  = perms[p * NTOT + i];
        int bY = perms[p * NTOT + NHALF + i];
        float si  = bf2f(STT[p * NTOT + i]);
        float si2 = bf2f(STT[p * NTOT + NHALF + i]);
#pragma unroll
        for (int k = 0; k < NKER; ++k) {
            v[k * 4 + 0] += ws[OF_ROWM + k * NTOT + a];
            v[k * 4 + 1] += ws[OF_COLM + k * NTOT + a];
            float kv = bf2f(KH[k * K0SZ + a * NTOT + bY]);
            if (a < NHALF && bY == a + NHALF) kv = 0.f;
            v[k * 4 + 2] += kv;
            v[k * 4 + 3] += ws[OF_C + k * NHALF + i] * si * si2;
        }
    }
#pragma unroll
    for (int off = 32; off > 0; off >>= 1)
#pragma unroll
        for (int j = 0; j < 16; ++j) v[j] += __shfl_down(v[j], off, 64);
    __syncthreads();
    if (lane == 0)
#pragma unroll
        for (int j = 0; j < 16; ++j) smem[wave * 16 + j] = v[j];
    __syncthreads();
    if (tid < 16) smem[64 + tid] = smem[tid] + smem[16 + tid] + smem[32 + tid] + smem[48 + tid];
    __syncthreads();
    if (tid < NKER) {
        int k = tid;
        double rs = smem[64 + k * 4 + 0], cs = smem[64 + k * 4 + 1];
        double pair = smem[64 + k * 4 + 2], qc = smem[64 + k * 4 + 3];
        double total_mod = (double)ws[OF_SCAL + k * 4 + 0];
        double dk        = (double)ws[OF_SCAL + k * 4 + 1];
        double q = -qc;
#pragma unroll
        for (int mb = 0; mb < NMB; ++mb) q += (double)ws[OF_Q0P + (k * NMB + mb) * PPAD + p];
        double sXX = q - 384.0 * dk;
        double sYY = total_mod - rs - cs + q - 384.0 * dk;
        double sXY = rs - q - pair;
        out[k * 201 + 1 + p] =
            (float)(sXX * (1.0 / 147072.0) + sYY * (1.0 / 147072.0) - 2.0 * sXY * (1.0 / 147456.0));
    }
}

extern "C" void kernel_launch(void* const* d_in, const int* in_sizes, int n_in,
                              void* d_out, int out_size, void* d_ws, size_t ws_size,
                              hipStream_t stream) {
    const float* X     = (const float*)d_in[0];
    const float* Y     = (const float*)d_in[1];
    const float* bw    = (const float*)d_in[2];
    const int*   perms = (const int*)d_in[3];
    float* ws  = (float*)d_ws;
    float* out = (float*)d_out;

    k_s1<<<NPER + NHALF, 256, 0, stream>>>(X, Y, bw, perms, ws);
    k_s2<<<NB_GEMM + NKER, 256, 0, stream>>>(bw, ws, out);
    k_s3<<<NPER, 256, 0, stream>>>(perms, ws, out);
}

// Round 8
// 107.655 us; speedup vs baseline: 2.6362x; 1.0494x over previous
//
#include <hip/hip_runtime.h>

#define NTOT 768
#define NHALF 384
#define DDIM 64
#define NPER 200
#define PPAD 256
#define NKER 4
#define CHUNK 192
#define NMB 12       // m-blocks of 64 rows
#define NKH 2        // split-K halves
#define NB_GEMM 384  // 12 mb * 4 nc * 4 k * 2 kh
#define NPART (NMB * NKH)

typedef __attribute__((ext_vector_type(8))) short short8;    // 8 bf16 (4 VGPR)
typedef __attribute__((ext_vector_type(4))) float floatx4;   // MFMA acc

constexpr int K0SZ  = NTOT * NTOT;
constexpr int OF_KH = 0;                                  // bf16 K [4][768][768] (ushort)
constexpr int KH_FLOATS = NKER * K0SZ / 2;
constexpr int OF_RS0 = OF_KH + KH_FLOATS;
constexpr int OF_RSX = OF_RS0 + NKER * NTOT;
constexpr int OF_RSY = OF_RSX + NKER * NTOT;
constexpr int OF_C   = OF_RSY + NKER * NTOT;
constexpr int OF_ROWM = OF_C + NKER * NHALF;
constexpr int OF_COLM = OF_ROWM + NKER * NTOT;
constexpr int OF_SCAL = OF_COLM + NKER * NTOT;
constexpr int OF_STT  = OF_SCAL + 16;                     // bf16 S^T [PPAD][NTOT]
constexpr int STT_FLOATS = PPAD * NTOT / 2;
constexpr int OF_Q0P  = OF_STT + STT_FLOATS;              // fp32 [4][NPART][PPAD] partials

// smem: zb[CHUNK*65] + zaS[64] + redw[32] = 12576 floats = 50304 B → 3 blocks/CU
constexpr int SMEMF = CHUNK * 65 + DDIM + 32;

__device__ __forceinline__ unsigned short f2bf(float f) {  // RTN
    unsigned int u = __float_as_uint(f);
    return (unsigned short)((u + 0x7FFFu + ((u >> 16) & 1u)) >> 16);
}
__device__ __forceinline__ float bf2f(unsigned short h) {
    return __uint_as_float(((unsigned int)h) << 16);
}

// ============ stage 1: scatter STT (bid<200) or single-row K build (row a=bid-200) ============
// block count beats per-block efficiency here (R7 lesson: 2-row fusion regressed)
__global__ __launch_bounds__(256) void k_s1(const float* __restrict__ X,
                                            const float* __restrict__ Y,
                                            const float* __restrict__ bw,
                                            const int* __restrict__ perms,
                                            float* __restrict__ ws) {
    __shared__ float smem[SMEMF];
    float* zb   = smem;
    float* zaS  = smem + CHUNK * 65;
    float* redw = zaS + DDIM;
    int bid = blockIdx.x, tid = threadIdx.x;
    int wave = tid >> 6, lane = tid & 63;
    unsigned short* STT = (unsigned short*)(ws + OF_STT);
    unsigned short* KH  = (unsigned short*)(ws + OF_KH);

    if (bid < NPER) {
        if (tid < 192) {
            ((uint2*)(STT + bid * NTOT))[tid] = make_uint2(0u, 0u);
            if (bid < PPAD - NPER)
                ((uint2*)(STT + (NPER + bid) * NTOT))[tid] = make_uint2(0u, 0u);
        }
        __syncthreads();
        int v = perms[bid * NTOT + tid];
        STT[bid * NTOT + v] = 0x3F80;  // bf16 1.0
        if (tid < NHALF - 256) {
            int v2 = perms[bid * NTOT + 256 + tid];
            STT[bid * NTOT + v2] = 0x3F80;
        }
        return;
    }

    int a = bid - NPER;
    const float* za = (a < NHALF) ? X + a * DDIM : Y + (a - NHALF) * DDIM;
    if (tid < DDIM) zaS[tid] = za[tid];
    float ib2[NKER], ib1[NKER];
#pragma unroll
    for (int k = 0; k < NKER; ++k) { float b = bw[k]; ib2[k] = 1.f / (b * b); ib1[k] = 1.f / b; }
    __syncthreads();
    float sqa = 0.f;
#pragma unroll
    for (int d = 0; d < DDIM; ++d) sqa = fmaf(zaS[d], zaS[d], sqa);
    float accX[NKER] = {0.f, 0.f, 0.f, 0.f};
    float accY[NKER] = {0.f, 0.f, 0.f, 0.f};

    for (int c0 = 0; c0 < NTOT; c0 += CHUNK) {
        __syncthreads();
        for (int idx = tid; idx < CHUNK * DDIM; idx += 256) {
            int r = idx >> 6, d = idx & 63;
            int gr = c0 + r;
            const float* zr = (gr < NHALF) ? X + gr * DDIM : Y + (gr - NHALF) * DDIM;
            zb[r * 65 + d] = zr[d];
        }
        __syncthreads();
        if (tid < CHUNK) {
            int b = c0 + tid;
            float dot = 0.f, sqb = 0.f;
#pragma unroll
            for (int d = 0; d < DDIM; ++d) {
                float zv = zb[tid * 65 + d];
                dot = fmaf(zaS[d], zv, dot);
                sqb = fmaf(zv, zv, sqb);
            }
            float d2 = (sqa + sqb) - 2.f * dot;
            if (b == a) d2 = 0.f;
            d2 = fmaxf(d2, 0.f);
            float d2e = d2 + 1e-12f;
            float dist = sqrtf(d2e);
#pragma unroll
            for (int k = 0; k < NKER; ++k) {
                float val = ((k & 1) == 0) ? __expf(-d2e * ib2[k]) : __expf(-dist * ib1[k]);
                KH[k * K0SZ + a * NTOT + b] = f2bf(val);
                if (b < NHALF) accX[k] += val; else accY[k] += val;
                if (a < NHALF && b == a + NHALF) ws[OF_C + k * NHALF + a] = val;
            }
        }
    }
    float vals[8];
#pragma unroll
    for (int k = 0; k < NKER; ++k) { vals[k] = accX[k]; vals[4 + k] = accY[k]; }
#pragma unroll
    for (int off = 32; off > 0; off >>= 1)
#pragma unroll
        for (int v = 0; v < 8; ++v) vals[v] += __shfl_down(vals[v], off, 64);
    __syncthreads();
    if (lane == 0)
#pragma unroll
        for (int v = 0; v < 8; ++v) redw[wave * 8 + v] = vals[v];
    __syncthreads();
    if (tid == 0) {
#pragma unroll
        for (int k = 0; k < NKER; ++k) {
            float sx = redw[k] + redw[8 + k] + redw[16 + k] + redw[24 + k];
            float sy = redw[4 + k] + redw[12 + k] + redw[20 + k] + redw[28 + k];
            ws[OF_RS0 + k * NTOT + a] = sx + sy;
            ws[OF_RSX + k * NTOT + a] = sx;
            ws[OF_RSY + k * NTOT + a] = sy;
        }
    }
}

// ============ stage 2: split-K gemm (bid<384) or final (k=bid-384) ============
__global__ __launch_bounds__(256) void k_s2(const float* __restrict__ bw,
                                            float* __restrict__ ws, float* __restrict__ out) {
    __shared__ float smem[256];
    int bid = blockIdx.x, tid = threadIdx.x;
    int wave = tid >> 6, lane = tid & 63;

    if (bid < NB_GEMM) {
        int mb = bid % NMB;
        int t  = bid / NMB;
        int nc = t & 3;
        int t2 = t >> 2;
        int k  = t2 & 3;
        int kh = t2 >> 2;
        int m0 = mb * 64 + wave * 16;
        int n0 = nc * 64;
        int row = lane & 15, quad = lane >> 4;
        const unsigned short* KH  = (const unsigned short*)(ws + OF_KH);
        const unsigned short* STT = (const unsigned short*)(ws + OF_STT);
        const unsigned short* aptr = KH + k * K0SZ + (m0 + row) * NTOT + quad * 8;
        floatx4 acc[4][2];
#pragma unroll
        for (int j = 0; j < 4; ++j)
#pragma unroll
            for (int h = 0; h < 2; ++h) acc[j][h] = (floatx4){0.f, 0.f, 0.f, 0.f};
        int kk0 = kh * (NTOT / 2);
        for (int kk = kk0; kk < kk0 + NTOT / 2; kk += 64) {
            short8 a0 = *(const short8*)(aptr + kk);
            short8 a1 = *(const short8*)(aptr + kk + 32);
#pragma unroll
            for (int j = 0; j < 4; ++j) {
                const unsigned short* bp = STT + (n0 + j * 16 + row) * NTOT + quad * 8 + kk;
                short8 b0 = *(const short8*)(bp);
                short8 b1 = *(const short8*)(bp + 32);
                acc[j][0] = __builtin_amdgcn_mfma_f32_16x16x32_bf16(a0, b0, acc[j][0], 0, 0, 0);
                acc[j][1] = __builtin_amdgcn_mfma_f32_16x16x32_bf16(a1, b1, acc[j][1], 0, 0, 0);
            }
        }
        __syncthreads();
        // epilogue: ⊙S + column-reduce (linear in split-K partials)
#pragma unroll
        for (int j = 0; j < 4; ++j) {
            const unsigned short* sp = STT + (n0 + j * 16 + row) * NTOT + m0 + quad * 4;
            float p = 0.f;
#pragma unroll
            for (int r = 0; r < 4; ++r) p += (acc[j][0][r] + acc[j][1][r]) * bf2f(sp[r]);
            p += __shfl_down(p, 32, 64);
            p += __shfl_down(p, 16, 64);
            if (lane < 16) smem[wave * 64 + j * 16 + lane] = p;
        }
        __syncthreads();
        if (tid < 64) {
            float s = smem[tid] + smem[64 + tid] + smem[128 + tid] + smem[192 + tid];
            ws[OF_Q0P + (k * NPART + kh * NMB + mb) * PPAD + n0 + tid] = s;
        }
        return;
    }

    int k = bid - NB_GEMM;
    float v[5] = {0.f, 0.f, 0.f, 0.f, 0.f};
    for (int a = tid; a < NTOT; a += 256) v[0] += ws[OF_RS0 + k * NTOT + a];
    for (int a = tid; a < NHALF; a += 256) {
        v[1] += ws[OF_C + k * NHALF + a];
        v[2] += ws[OF_RSX + k * NTOT + a];
        v[3] += ws[OF_RSY + k * NTOT + NHALF + a];
        v[4] += ws[OF_RSY + k * NTOT + a];
    }
#pragma unroll
    for (int off = 32; off > 0; off >>= 1)
#pragma unroll
        for (int j = 0; j < 5; ++j) v[j] += __shfl_down(v[j], off, 64);
    __syncthreads();
    if (lane == 0)
#pragma unroll
        for (int j = 0; j < 5; ++j) smem[wave * 8 + j] = v[j];
    __syncthreads();
    if (tid == 0) {
        float tot0 = smem[0] + smem[8] + smem[16] + smem[24];
        float csum = smem[1] + smem[9] + smem[17] + smem[25];
        float sxx  = smem[2] + smem[10] + smem[18] + smem[26];
        float syy  = smem[3] + smem[11] + smem[19] + smem[27];
        float sxy  = smem[4] + smem[12] + smem[20] + smem[28];
        float b = bw[k];
        float dist0 = sqrtf(1e-12f);
        float dk = ((k & 1) == 0) ? expf(-(dist0 * dist0) / (b * b)) : expf(-dist0 / b);
        ws[OF_SCAL + k * 4 + 0] = tot0 - csum;
        ws[OF_SCAL + k * 4 + 1] = dk;
        double U = ((double)sxx - 384.0 * (double)dk) * (1.0 / 147072.0)
                 + ((double)syy - 384.0 * (double)dk) * (1.0 / 147072.0)
                 - 2.0 * ((double)sxy - (double)csum) * (1.0 / 147456.0);
        out[k * 201] = (float)U;
    }
    for (int idx = tid; idx < NTOT; idx += 256) {
        float r0 = ws[OF_RS0 + k * NTOT + idx];
        float cx = (idx < NHALF)  ? ws[OF_C + k * NHALF + idx] : 0.f;
        float cy = (idx >= NHALF) ? ws[OF_C + k * NHALF + idx - NHALF] : 0.f;
        ws[OF_ROWM + k * NTOT + idx] = r0 - cx;
        ws[OF_COLM + k * NTOT + idx] = r0 - cy;
    }
}

// ============ stage 3: per-permutation gathered sums + final U_b ============
__global__ __launch_bounds__(256) void k_s3(const int* __restrict__ perms,
                                            const float* __restrict__ ws,
                                            float* __restrict__ out) {
    __shared__ float smem[128];
    int p = blockIdx.x, tid = threadIdx.x;
    int wave = tid >> 6, lane = tid & 63;
    const unsigned short* STT = (const unsigned short*)(ws + OF_STT);
    const unsigned short* KH  = (const unsigned short*)(ws + OF_KH);
    float v[16] = {0.f};  // [k][rs, cs, pair, qc]
    for (int i = tid; i < NHALF; i += 256) {
        int a  = perms[p * NTOT + i];
        int bY = perms[p * NTOT + NHALF + i];
        float si  = bf2f(STT[p * NTOT + i]);
        float si2 = bf2f(STT[p * NTOT + NHALF + i]);
#pragma unroll
        for (int k = 0; k < NKER; ++k) {
            v[k * 4 + 0] += ws[OF_ROWM + k * NTOT + a];
            v[k * 4 + 1] += ws[OF_COLM + k * NTOT + a];
            float kv = bf2f(KH[k * K0SZ + a * NTOT + bY]);
            if (a < NHALF && bY == a + NHALF) kv = 0.f;
            v[k * 4 + 2] += kv;
            v[k * 4 + 3] += ws[OF_C + k * NHALF + i] * si * si2;
        }
    }
#pragma unroll
    for (int off = 32; off > 0; off >>= 1)
#pragma unroll
        for (int j = 0; j < 16; ++j) v[j] += __shfl_down(v[j], off, 64);
    __syncthreads();
    if (lane == 0)
#pragma unroll
        for (int j = 0; j < 16; ++j) smem[wave * 16 + j] = v[j];
    __syncthreads();
    if (tid < 16) smem[64 + tid] = smem[tid] + smem[16 + tid] + smem[32 + tid] + smem[48 + tid];
    __syncthreads();
    if (tid < NKER) {
        int k = tid;
        double rs = smem[64 + k * 4 + 0], cs = smem[64 + k * 4 + 1];
        double pair = smem[64 + k * 4 + 2], qc = smem[64 + k * 4 + 3];
        double total_mod = (double)ws[OF_SCAL + k * 4 + 0];
        double dk        = (double)ws[OF_SCAL + k * 4 + 1];
        double q = -qc;
#pragma unroll
        for (int j = 0; j < NPART; ++j) q += (double)ws[OF_Q0P + (k * NPART + j) * PPAD + p];
        double sXX = q - 384.0 * dk;
        double sYY = total_mod - rs - cs + q - 384.0 * dk;
        double sXY = rs - q - pair;
        out[k * 201 + 1 + p] =
            (float)(sXX * (1.0 / 147072.0) + sYY * (1.0 / 147072.0) - 2.0 * sXY * (1.0 / 147456.0));
    }
}

extern "C" void kernel_launch(void* const* d_in, const int* in_sizes, int n_in,
                              void* d_out, int out_size, void* d_ws, size_t ws_size,
                              hipStream_t stream) {
    const float* X     = (const float*)d_in[0];
    const float* Y     = (const float*)d_in[1];
    const float* bw    = (const float*)d_in[2];
    const int*   perms = (const int*)d_in[3];
    float* ws  = (float*)d_ws;
    float* out = (float*)d_out;

    k_s1<<<NPER + NTOT, 256, 0, stream>>>(X, Y, bw, perms, ws);
    k_s2<<<NB_GEMM + NKER, 256, 0, stream>>>(bw, ws, out);
    k_s3<<<NPER, 256, 0, stream>>>(perms, ws, out);
}

// Round 9
// 105.026 us; speedup vs baseline: 2.7022x; 1.0250x over previous
//
#include <hip/hip_runtime.h>

#define NTOT 768
#define NHALF 384
#define DDIM 64
#define NPER 200
#define PPAD 256
#define NKER 4
#define NMB 12       // m-blocks of 64 rows (gemm)
#define NKH 2        // split-K halves (gemm)
#define NB_GEMM 384  // 12 mb * 4 nc * 4 k * 2 kh
#define NPART (NMB * NKH)
#define NTILE 12     // 768/64 K-build tiles per dim
#define LDSROW 68    // float stride per staged row: 16B-aligned, 2-way-max banks

typedef __attribute__((ext_vector_type(8))) short short8;    // 8 bf16 (4 VGPR)
typedef __attribute__((ext_vector_type(4))) float floatx4;   // MFMA acc

constexpr int K0SZ  = NTOT * NTOT;
constexpr int OF_KH = 0;                                  // bf16 K [4][768][768] (ushort)
constexpr int KH_FLOATS = NKER * K0SZ / 2;
constexpr int OF_P   = OF_KH + KH_FLOATS;                 // fp32 row-sum partials [4][12][768]
constexpr int OF_C   = OF_P + NKER * NTILE * NTOT;
constexpr int OF_ROWM = OF_C + NKER * NHALF;
constexpr int OF_COLM = OF_ROWM + NKER * NTOT;
constexpr int OF_SCAL = OF_COLM + NKER * NTOT;
constexpr int OF_STT  = OF_SCAL + 16;                     // bf16 S^T [PPAD][NTOT]
constexpr int STT_FLOATS = PPAD * NTOT / 2;
constexpr int OF_Q0P  = OF_STT + STT_FLOATS;              // fp32 [4][NPART][PPAD]

__device__ __forceinline__ unsigned short f2bf(float f) {  // RTN
    unsigned int u = __float_as_uint(f);
    return (unsigned short)((u + 0x7FFFu + ((u >> 16) & 1u)) >> 16);
}
__device__ __forceinline__ float bf2f(unsigned short h) {
    return __uint_as_float(((unsigned int)h) << 16);
}

// ============ stage 1: scatter STT (bid<200) or 64x64 K tile build (bid-200) ============
// 2D tiling: 144 tile blocks read 128 Z rows each (4.7 MB total vs 190 MB row-wise),
// 4x4 register micro-tile, float4 LDS reads (stride-68 rows: conflict-free), ushort4 stores.
__global__ __launch_bounds__(256) void k_s1(const float* __restrict__ X,
                                            const float* __restrict__ Y,
                                            const float* __restrict__ bw,
                                            const int* __restrict__ perms,
                                            float* __restrict__ ws) {
    __shared__ float smem[128 * LDSROW + 128];   // zb rows + norms = 35 KB
    float* zb  = smem;
    float* nrm = smem + 128 * LDSROW;
    int bid = blockIdx.x, tid = threadIdx.x;
    unsigned short* STT = (unsigned short*)(ws + OF_STT);
    unsigned short* KH  = (unsigned short*)(ws + OF_KH);

    if (bid < NPER) {
        if (tid < 192) {
            ((uint2*)(STT + bid * NTOT))[tid] = make_uint2(0u, 0u);
            if (bid < PPAD - NPER)
                ((uint2*)(STT + (NPER + bid) * NTOT))[tid] = make_uint2(0u, 0u);
        }
        __syncthreads();
        int v = perms[bid * NTOT + tid];
        STT[bid * NTOT + v] = 0x3F80;  // bf16 1.0
        if (tid < NHALF - 256) {
            int v2 = perms[bid * NTOT + 256 + tid];
            STT[bid * NTOT + v2] = 0x3F80;
        }
        return;
    }

    int t  = bid - NPER;           // 0..143
    int at = t / NTILE, bt = t % NTILE;
    int a0 = at * 64, b0 = bt * 64;
    int ta = tid >> 4, tb = tid & 15;

    float ib2[NKER], ib1[NKER];
#pragma unroll
    for (int k = 0; k < NKER; ++k) { float b = bw[k]; ib2[k] = 1.f / (b * b); ib1[k] = 1.f / b; }

    // stage 128 rows (64 a-rows then 64 b-rows), coalesced float4
#pragma unroll
    for (int it = 0; it < 8; ++it) {
        int idx = it * 256 + tid;
        int j = idx >> 4, qf = idx & 15;
        int g = (j < 64) ? a0 + j : b0 + (j - 64);
        const float* zr = (g < NHALF) ? X + g * DDIM : Y + (g - NHALF) * DDIM;
        *(float4*)(zb + j * LDSROW + qf * 4) = *(const float4*)(zr + qf * 4);
    }
    __syncthreads();
    if (tid < 128) {
        float s = 0.f;
        const float* zr = zb + tid * LDSROW;
#pragma unroll
        for (int d = 0; d < DDIM; d += 4) {
            float4 zv = *(const float4*)(zr + d);
            s += zv.x * zv.x + zv.y * zv.y + zv.z * zv.z + zv.w * zv.w;
        }
        nrm[tid] = s;
    }
    __syncthreads();

    // 4x4 micro-tile dot products
    float acc[4][4];
#pragma unroll
    for (int r = 0; r < 4; ++r)
#pragma unroll
        for (int c = 0; c < 4; ++c) acc[r][c] = 0.f;
#pragma unroll
    for (int s = 0; s < 16; ++s) {
        float4 av[4], bv[4];
#pragma unroll
        for (int r = 0; r < 4; ++r) av[r] = *(const float4*)(zb + (ta * 4 + r) * LDSROW + s * 4);
#pragma unroll
        for (int c = 0; c < 4; ++c) bv[c] = *(const float4*)(zb + (64 + tb * 4 + c) * LDSROW + s * 4);
#pragma unroll
        for (int r = 0; r < 4; ++r)
#pragma unroll
            for (int c = 0; c < 4; ++c) {
                acc[r][c] = fmaf(av[r].x, bv[c].x, acc[r][c]);
                acc[r][c] = fmaf(av[r].y, bv[c].y, acc[r][c]);
                acc[r][c] = fmaf(av[r].z, bv[c].z, acc[r][c]);
                acc[r][c] = fmaf(av[r].w, bv[c].w, acc[r][c]);
            }
    }

    // epilogue: 4 kernels, bf16 pack (ushort4 along b), row-sum partials
    float rs[4][NKER];
#pragma unroll
    for (int r = 0; r < 4; ++r)
#pragma unroll
        for (int k = 0; k < NKER; ++k) rs[r][k] = 0.f;

#pragma unroll
    for (int r = 0; r < 4; ++r) {
        int a = a0 + ta * 4 + r;
        ushort4 us[NKER];
#pragma unroll
        for (int c = 0; c < 4; ++c) {
            int b = b0 + tb * 4 + c;
            float d2 = (nrm[ta * 4 + r] + nrm[64 + tb * 4 + c]) - 2.f * acc[r][c];
            if (b == a) d2 = 0.f;
            d2 = fmaxf(d2, 0.f);
            float d2e = d2 + 1e-12f;
            float dist = sqrtf(d2e);
#pragma unroll
            for (int k = 0; k < NKER; ++k) {
                float val = ((k & 1) == 0) ? __expf(-d2e * ib2[k]) : __expf(-dist * ib1[k]);
                rs[r][k] += val;
                unsigned short h = f2bf(val);
                if (c == 0) us[k].x = h; else if (c == 1) us[k].y = h;
                else if (c == 2) us[k].z = h; else us[k].w = h;
                if (bt == at + 6 && tb == ta && c == r)   // b == a+384, a<384
                    ws[OF_C + k * NHALF + a] = val;
            }
        }
#pragma unroll
        for (int k = 0; k < NKER; ++k)
            *(ushort4*)(KH + k * K0SZ + a * NTOT + b0 + tb * 4) = us[k];
    }

    // reduce rs over tb (16 lanes) and write partials P[k][bt][a0+ta*4 .. +3]
#pragma unroll
    for (int off = 8; off > 0; off >>= 1)
#pragma unroll
        for (int r = 0; r < 4; ++r)
#pragma unroll
            for (int k = 0; k < NKER; ++k) rs[r][k] += __shfl_down(rs[r][k], off, 64);
    if (tb == 0) {
#pragma unroll
        for (int k = 0; k < NKER; ++k) {
            float4 pv = make_float4(rs[0][k], rs[1][k], rs[2][k], rs[3][k]);
            *(float4*)(ws + OF_P + (k * NTILE + bt) * NTOT + a0 + ta * 4) = pv;
        }
    }
}

// ============ stage 2: split-K gemm (bid<384) or final (k=bid-384) ============
__global__ __launch_bounds__(256) void k_s2(const float* __restrict__ bw,
                                            float* __restrict__ ws, float* __restrict__ out) {
    __shared__ float smem[256];
    int bid = blockIdx.x, tid = threadIdx.x;
    int wave = tid >> 6, lane = tid & 63;

    if (bid < NB_GEMM) {
        int mb = bid % NMB;
        int t  = bid / NMB;
        int nc = t & 3;
        int t2 = t >> 2;
        int k  = t2 & 3;
        int kh = t2 >> 2;
        int m0 = mb * 64 + wave * 16;
        int n0 = nc * 64;
        int row = lane & 15, quad = lane >> 4;
        const unsigned short* KH  = (const unsigned short*)(ws + OF_KH);
        const unsigned short* STT = (const unsigned short*)(ws + OF_STT);
        const unsigned short* aptr = KH + k * K0SZ + (m0 + row) * NTOT + quad * 8;
        floatx4 acc[4][2];
#pragma unroll
        for (int j = 0; j < 4; ++j)
#pragma unroll
            for (int h = 0; h < 2; ++h) acc[j][h] = (floatx4){0.f, 0.f, 0.f, 0.f};
        int kk0 = kh * (NTOT / 2);
        for (int kk = kk0; kk < kk0 + NTOT / 2; kk += 64) {
            short8 a0 = *(const short8*)(aptr + kk);
            short8 a1 = *(const short8*)(aptr + kk + 32);
#pragma unroll
            for (int j = 0; j < 4; ++j) {
                const unsigned short* bp = STT + (n0 + j * 16 + row) * NTOT + quad * 8 + kk;
                short8 b0 = *(const short8*)(bp);
                short8 b1 = *(const short8*)(bp + 32);
                acc[j][0] = __builtin_amdgcn_mfma_f32_16x16x32_bf16(a0, b0, acc[j][0], 0, 0, 0);
                acc[j][1] = __builtin_amdgcn_mfma_f32_16x16x32_bf16(a1, b1, acc[j][1], 0, 0, 0);
            }
        }
        __syncthreads();
#pragma unroll
        for (int j = 0; j < 4; ++j) {
            const unsigned short* sp = STT + (n0 + j * 16 + row) * NTOT + m0 + quad * 4;
            float p = 0.f;
#pragma unroll
            for (int r = 0; r < 4; ++r) p += (acc[j][0][r] + acc[j][1][r]) * bf2f(sp[r]);
            p += __shfl_down(p, 32, 64);
            p += __shfl_down(p, 16, 64);
            if (lane < 16) smem[wave * 64 + j * 16 + lane] = p;
        }
        __syncthreads();
        if (tid < 64) {
            float s = smem[tid] + smem[64 + tid] + smem[128 + tid] + smem[192 + tid];
            ws[OF_Q0P + (k * NPART + kh * NMB + mb) * PPAD + n0 + tid] = s;
        }
        return;
    }

    int k = bid - NB_GEMM;
    const float* Pk = ws + OF_P + k * (NTILE * NTOT);
    float v[5] = {0.f, 0.f, 0.f, 0.f, 0.f};
    for (int a = tid; a < NTOT; a += 256) {
        float rsx = 0.f, rsy = 0.f;
#pragma unroll
        for (int j = 0; j < 6; ++j)  rsx += Pk[j * NTOT + a];
#pragma unroll
        for (int j = 6; j < 12; ++j) rsy += Pk[j * NTOT + a];
        float rs0 = rsx + rsy;
        float cx = (a < NHALF)  ? ws[OF_C + k * NHALF + a] : 0.f;
        float cy = (a >= NHALF) ? ws[OF_C + k * NHALF + a - NHALF] : 0.f;
        ws[OF_ROWM + k * NTOT + a] = rs0 - cx;
        ws[OF_COLM + k * NTOT + a] = rs0 - cy;
        v[0] += rs0;
        if (a < NHALF) { v[1] += cx; v[2] += rsx; v[4] += rsy; }
        else           { v[3] += rsy; }
    }
#pragma unroll
    for (int off = 32; off > 0; off >>= 1)
#pragma unroll
        for (int j = 0; j < 5; ++j) v[j] += __shfl_down(v[j], off, 64);
    __syncthreads();
    if (lane == 0)
#pragma unroll
        for (int j = 0; j < 5; ++j) smem[wave * 8 + j] = v[j];
    __syncthreads();
    if (tid == 0) {
        float tot0 = smem[0] + smem[8] + smem[16] + smem[24];
        float csum = smem[1] + smem[9] + smem[17] + smem[25];
        float sxx  = smem[2] + smem[10] + smem[18] + smem[26];
        float syy  = smem[3] + smem[11] + smem[19] + smem[27];
        float sxy  = smem[4] + smem[12] + smem[20] + smem[28];
        float b = bw[k];
        float dist0 = sqrtf(1e-12f);
        float dk = ((k & 1) == 0) ? expf(-(dist0 * dist0) / (b * b)) : expf(-dist0 / b);
        ws[OF_SCAL + k * 4 + 0] = tot0 - csum;
        ws[OF_SCAL + k * 4 + 1] = dk;
        double U = ((double)sxx - 384.0 * (double)dk) * (1.0 / 147072.0)
                 + ((double)syy - 384.0 * (double)dk) * (1.0 / 147072.0)
                 - 2.0 * ((double)sxy - (double)csum) * (1.0 / 147456.0);
        out[k * 201] = (float)U;
    }
}

// ============ stage 3: per-permutation gathered sums + final U_b ============
__global__ __launch_bounds__(256) void k_s3(const int* __restrict__ perms,
                                            const float* __restrict__ ws,
                                            float* __restrict__ out) {
    __shared__ float smem[128];
    int p = blockIdx.x, tid = threadIdx.x;
    int wave = tid >> 6, lane = tid & 63;
    const unsigned short* STT = (const unsigned short*)(ws + OF_STT);
    const unsigned short* KH  = (const unsigned short*)(ws + OF_KH);
    float v[16] = {0.f};  // [k][rs, cs, pair, qc]
    for (int i = tid; i < NHALF; i += 256) {
        int a  = perms[p * NTOT + i];
        int bY = perms[p * NTOT + NHALF + i];
        float si  = bf2f(STT[p * NTOT + i]);
        float si2 = bf2f(STT[p * NTOT + NHALF + i]);
#pragma unroll
        for (int k = 0; k < NKER; ++k) {
            v[k * 4 + 0] += ws[OF_ROWM + k * NTOT + a];
            v[k * 4 + 1] += ws[OF_COLM + k * NTOT + a];
            float kv = bf2f(KH[k * K0SZ + a * NTOT + bY]);
            if (a < NHALF && bY == a + NHALF) kv = 0.f;
            v[k * 4 + 2] += kv;
            v[k * 4 + 3] += ws[OF_C + k * NHALF + i] * si * si2;
        }
    }
#pragma unroll
    for (int off = 32; off > 0; off >>= 1)
#pragma unroll
        for (int j = 0; j < 16; ++j) v[j] += __shfl_down(v[j], off, 64);
    __syncthreads();
    if (lane == 0)
#pragma unroll
        for (int j = 0; j < 16; ++j) smem[wave * 16 + j] = v[j];
    __syncthreads();
    if (tid < 16) smem[64 + tid] = smem[tid] + smem[16 + tid] + smem[32 + tid] + smem[48 + tid];
    __syncthreads();
    if (tid < NKER) {
        int k = tid;
        double rs = smem[64 + k * 4 + 0], cs = smem[64 + k * 4 + 1];
        double pair = smem[64 + k * 4 + 2], qc = smem[64 + k * 4 + 3];
        double total_mod = (double)ws[OF_SCAL + k * 4 + 0];
        double dk        = (double)ws[OF_SCAL + k * 4 + 1];
        double q = -qc;
#pragma unroll
        for (int j = 0; j < NPART; ++j) q += (double)ws[OF_Q0P + (k * NPART + j) * PPAD + p];
        double sXX = q - 384.0 * dk;
        double sYY = total_mod - rs - cs + q - 384.0 * dk;
        double sXY = rs - q - pair;
        out[k * 201 + 1 + p] =
            (float)(sXX * (1.0 / 147072.0) + sYY * (1.0 / 147072.0) - 2.0 * sXY * (1.0 / 147456.0));
    }
}

extern "C" void kernel_launch(void* const* d_in, const int* in_sizes, int n_in,
                              void* d_out, int out_size, void* d_ws, size_t ws_size,
                              hipStream_t stream) {
    const float* X     = (const float*)d_in[0];
    const float* Y     = (const float*)d_in[1];
    const float* bw    = (const float*)d_in[2];
    const int*   perms = (const int*)d_in[3];
    float* ws  = (float*)d_ws;
    float* out = (float*)d_out;

    k_s1<<<NPER + NTILE * NTILE, 256, 0, stream>>>(X, Y, bw, perms, ws);
    k_s2<<<NB_GEMM + NKER, 256, 0, stream>>>(bw, ws, out);
    k_s3<<<NPER, 256, 0, stream>>>(perms, ws, out);
}

// Round 11
// 103.788 us; speedup vs baseline: 2.7345x; 1.0119x over previous
//
#include <hip/hip_runtime.h>

#define NTOT 768
#define NHALF 384
#define DDIM 64
#define NPER 200
#define PPAD 256
#define NKER 4
#define NMB 12       // m-blocks of 64 rows (gemm)
#define NKH 2        // split-K halves (gemm)
#define NB_GEMM 384  // 12 mb * 4 nc * 4 k * 2 kh
#define NPART (NMB * NKH)
#define NTILE 12     // 768/64 K-build tiles per dim
#define LDSROW 68    // float stride per staged row: 16B-aligned, 2-way-max banks

typedef __attribute__((ext_vector_type(8))) short short8;    // 8 bf16 (4 VGPR)
typedef __attribute__((ext_vector_type(4))) float floatx4;   // MFMA acc

constexpr int K0SZ  = NTOT * NTOT;
constexpr int OF_KH = 0;                                  // bf16 K [4][768][768] (ushort)
constexpr int KH_FLOATS = NKER * K0SZ / 2;
constexpr int OF_P   = OF_KH + KH_FLOATS;                 // fp32 row-sum partials [4][12][768]
constexpr int OF_C   = OF_P + NKER * NTILE * NTOT;
constexpr int OF_ROWM = OF_C + NKER * NHALF;
constexpr int OF_COLM = OF_ROWM + NKER * NTOT;
constexpr int OF_SCAL = OF_COLM + NKER * NTOT;
constexpr int OF_STT  = OF_SCAL + 16;                     // bf16 S^T [PPAD][NTOT]
constexpr int STT_FLOATS = PPAD * NTOT / 2;
constexpr int OF_Q0P  = OF_STT + STT_FLOATS;              // fp32 [4][NPART][PPAD]

__device__ __forceinline__ unsigned short f2bf(float f) {  // RTN
    unsigned int u = __float_as_uint(f);
    return (unsigned short)((u + 0x7FFFu + ((u >> 16) & 1u)) >> 16);
}
__device__ __forceinline__ float bf2f(unsigned short h) {
    return __uint_as_float(((unsigned int)h) << 16);
}

// ============ stage 1: scatter STT (bid<200) or 64x64 K tile build (bid-200) ============
// 2D tiling: 144 tile blocks read 128 Z rows each, 4x4 register micro-tile,
// float4 LDS reads (stride-68 rows: conflict-free), ushort4 KH stores.
__global__ __launch_bounds__(256) void k_s1(const float* __restrict__ X,
                                            const float* __restrict__ Y,
                                            const float* __restrict__ bw,
                                            const int* __restrict__ perms,
                                            float* __restrict__ ws) {
    __shared__ float smem[128 * LDSROW + 128];   // zb rows + norms = 35 KB
    float* zb  = smem;
    float* nrm = smem + 128 * LDSROW;
    int bid = blockIdx.x, tid = threadIdx.x;
    unsigned short* STT = (unsigned short*)(ws + OF_STT);
    unsigned short* KH  = (unsigned short*)(ws + OF_KH);

    if (bid < NPER) {
        if (tid < 192) {
            ((uint2*)(STT + bid * NTOT))[tid] = make_uint2(0u, 0u);
            if (bid < PPAD - NPER)
                ((uint2*)(STT + (NPER + bid) * NTOT))[tid] = make_uint2(0u, 0u);
        }
        __syncthreads();
        int v = perms[bid * NTOT + tid];
        STT[bid * NTOT + v] = 0x3F80;  // bf16 1.0
        if (tid < NHALF - 256) {
            int v2 = perms[bid * NTOT + 256 + tid];
            STT[bid * NTOT + v2] = 0x3F80;
        }
        return;
    }

    int t  = bid - NPER;           // 0..143
    int at = t / NTILE, bt = t % NTILE;
    int a0 = at * 64, b0 = bt * 64;
    int ta = tid >> 4, tb = tid & 15;

    float ib2[NKER], ib1[NKER];
#pragma unroll
    for (int k = 0; k < NKER; ++k) { float b = bw[k]; ib2[k] = 1.f / (b * b); ib1[k] = 1.f / b; }

#pragma unroll
    for (int it = 0; it < 8; ++it) {
        int idx = it * 256 + tid;
        int j = idx >> 4, qf = idx & 15;
        int g = (j < 64) ? a0 + j : b0 + (j - 64);
        const float* zr = (g < NHALF) ? X + g * DDIM : Y + (g - NHALF) * DDIM;
        *(float4*)(zb + j * LDSROW + qf * 4) = *(const float4*)(zr + qf * 4);
    }
    __syncthreads();
    if (tid < 128) {
        float s = 0.f;
        const float* zr = zb + tid * LDSROW;
#pragma unroll
        for (int d = 0; d < DDIM; d += 4) {
            float4 zv = *(const float4*)(zr + d);
            s += zv.x * zv.x + zv.y * zv.y + zv.z * zv.z + zv.w * zv.w;
        }
        nrm[tid] = s;
    }
    __syncthreads();

    float acc[4][4];
#pragma unroll
    for (int r = 0; r < 4; ++r)
#pragma unroll
        for (int c = 0; c < 4; ++c) acc[r][c] = 0.f;
#pragma unroll
    for (int s = 0; s < 16; ++s) {
        float4 av[4], bv[4];
#pragma unroll
        for (int r = 0; r < 4; ++r) av[r] = *(const float4*)(zb + (ta * 4 + r) * LDSROW + s * 4);
#pragma unroll
        for (int c = 0; c < 4; ++c) bv[c] = *(const float4*)(zb + (64 + tb * 4 + c) * LDSROW + s * 4);
#pragma unroll
        for (int r = 0; r < 4; ++r)
#pragma unroll
            for (int c = 0; c < 4; ++c) {
                acc[r][c] = fmaf(av[r].x, bv[c].x, acc[r][c]);
                acc[r][c] = fmaf(av[r].y, bv[c].y, acc[r][c]);
                acc[r][c] = fmaf(av[r].z, bv[c].z, acc[r][c]);
                acc[r][c] = fmaf(av[r].w, bv[c].w, acc[r][c]);
            }
    }

    float rs[4][NKER];
#pragma unroll
    for (int r = 0; r < 4; ++r)
#pragma unroll
        for (int k = 0; k < NKER; ++k) rs[r][k] = 0.f;

#pragma unroll
    for (int r = 0; r < 4; ++r) {
        int a = a0 + ta * 4 + r;
        ushort4 us[NKER];
#pragma unroll
        for (int c = 0; c < 4; ++c) {
            int b = b0 + tb * 4 + c;
            float d2 = (nrm[ta * 4 + r] + nrm[64 + tb * 4 + c]) - 2.f * acc[r][c];
            if (b == a) d2 = 0.f;
            d2 = fmaxf(d2, 0.f);
            float d2e = d2 + 1e-12f;
            float dist = sqrtf(d2e);
#pragma unroll
            for (int k = 0; k < NKER; ++k) {
                float val = ((k & 1) == 0) ? __expf(-d2e * ib2[k]) : __expf(-dist * ib1[k]);
                rs[r][k] += val;
                unsigned short h = f2bf(val);
                if (c == 0) us[k].x = h; else if (c == 1) us[k].y = h;
                else if (c == 2) us[k].z = h; else us[k].w = h;
                if (bt == at + 6 && tb == ta && c == r)   // b == a+384, a<384
                    ws[OF_C + k * NHALF + a] = val;
            }
        }
#pragma unroll
        for (int k = 0; k < NKER; ++k)
            *(ushort4*)(KH + k * K0SZ + a * NTOT + b0 + tb * 4) = us[k];
    }

#pragma unroll
    for (int off = 8; off > 0; off >>= 1)
#pragma unroll
        for (int r = 0; r < 4; ++r)
#pragma unroll
            for (int k = 0; k < NKER; ++k) rs[r][k] += __shfl_down(rs[r][k], off, 64);
    if (tb == 0) {
#pragma unroll
        for (int k = 0; k < NKER; ++k) {
            float4 pv = make_float4(rs[0][k], rs[1][k], rs[2][k], rs[3][k]);
            *(float4*)(ws + OF_P + (k * NTILE + bt) * NTOT + a0 + ta * 4) = pv;
        }
    }
}

// ============ stage 2: split-K gemm (bid<384) or final (k=bid-384) ============
__global__ __launch_bounds__(256) void k_s2(const float* __restrict__ bw,
                                            float* __restrict__ ws, float* __restrict__ out) {
    __shared__ float smem[256];
    int bid = blockIdx.x, tid = threadIdx.x;
    int wave = tid >> 6, lane = tid & 63;

    if (bid < NB_GEMM) {
        int mb = bid % NMB;
        int t  = bid / NMB;
        int nc = t & 3;
        int t2 = t >> 2;
        int k  = t2 & 3;
        int kh = t2 >> 2;
        int m0 = mb * 64 + wave * 16;
        int n0 = nc * 64;
        int row = lane & 15, quad = lane >> 4;
        const unsigned short* KH  = (const unsigned short*)(ws + OF_KH);
        const unsigned short* STT = (const unsigned short*)(ws + OF_STT);
        const unsigned short* aptr = KH + k * K0SZ + (m0 + row) * NTOT + quad * 8;
        floatx4 acc[4][2];
#pragma unroll
        for (int j = 0; j < 4; ++j)
#pragma unroll
            for (int h = 0; h < 2; ++h) acc[j][h] = (floatx4){0.f, 0.f, 0.f, 0.f};
        int kk0 = kh * (NTOT / 2);
        for (int kk = kk0; kk < kk0 + NTOT / 2; kk += 64) {
            short8 a0 = *(const short8*)(aptr + kk);
            short8 a1 = *(const short8*)(aptr + kk + 32);
#pragma unroll
            for (int j = 0; j < 4; ++j) {
                const unsigned short* bp = STT + (n0 + j * 16 + row) * NTOT + quad * 8 + kk;
                short8 b0 = *(const short8*)(bp);
                short8 b1 = *(const short8*)(bp + 32);
                acc[j][0] = __builtin_amdgcn_mfma_f32_16x16x32_bf16(a0, b0, acc[j][0], 0, 0, 0);
                acc[j][1] = __builtin_amdgcn_mfma_f32_16x16x32_bf16(a1, b1, acc[j][1], 0, 0, 0);
            }
        }
        __syncthreads();
#pragma unroll
        for (int j = 0; j < 4; ++j) {
            const unsigned short* sp = STT + (n0 + j * 16 + row) * NTOT + m0 + quad * 4;
            float p = 0.f;
#pragma unroll
            for (int r = 0; r < 4; ++r) p += (acc[j][0][r] + acc[j][1][r]) * bf2f(sp[r]);
            p += __shfl_down(p, 32, 64);
            p += __shfl_down(p, 16, 64);
            if (lane < 16) smem[wave * 64 + j * 16 + lane] = p;
        }
        __syncthreads();
        if (tid < 64) {
            float s = smem[tid] + smem[64 + tid] + smem[128 + tid] + smem[192 + tid];
            ws[OF_Q0P + (k * NPART + kh * NMB + mb) * PPAD + n0 + tid] = s;
        }
        return;
    }

    int k = bid - NB_GEMM;
    const float* Pk = ws + OF_P + k * (NTILE * NTOT);
    float v[5] = {0.f, 0.f, 0.f, 0.f, 0.f};
    for (int a = tid; a < NTOT; a += 256) {
        float rsx = 0.f, rsy = 0.f;
#pragma unroll
        for (int j = 0; j < 6; ++j)  rsx += Pk[j * NTOT + a];
#pragma unroll
        for (int j = 6; j < 12; ++j) rsy += Pk[j * NTOT + a];
        float rs0 = rsx + rsy;
        float cx = (a < NHALF)  ? ws[OF_C + k * NHALF + a] : 0.f;
        float cy = (a >= NHALF) ? ws[OF_C + k * NHALF + a - NHALF] : 0.f;
        ws[OF_ROWM + k * NTOT + a] = rs0 - cx;
        ws[OF_COLM + k * NTOT + a] = rs0 - cy;
        v[0] += rs0;
        if (a < NHALF) { v[1] += cx; v[2] += rsx; v[4] += rsy; }
        else           { v[3] += rsy; }
    }
#pragma unroll
    for (int off = 32; off > 0; off >>= 1)
#pragma unroll
        for (int j = 0; j < 5; ++j) v[j] += __shfl_down(v[j], off, 64);
    __syncthreads();
    if (lane == 0)
#pragma unroll
        for (int j = 0; j < 5; ++j) smem[wave * 8 + j] = v[j];
    __syncthreads();
    if (tid == 0) {
        float tot0 = smem[0] + smem[8] + smem[16] + smem[24];
        float csum = smem[1] + smem[9] + smem[17] + smem[25];
        float sxx  = smem[2] + smem[10] + smem[18] + smem[26];
        float syy  = smem[3] + smem[11] + smem[19] + smem[27];
        float sxy  = smem[4] + smem[12] + smem[20] + smem[28];
        float b = bw[k];
        float dist0 = sqrtf(1e-12f);
        float dk = ((k & 1) == 0) ? expf(-(dist0 * dist0) / (b * b)) : expf(-dist0 / b);
        ws[OF_SCAL + k * 4 + 0] = tot0 - csum;
        ws[OF_SCAL + k * 4 + 1] = dk;
        double U = ((double)sxx - 384.0 * (double)dk) * (1.0 / 147072.0)
                 + ((double)syy - 384.0 * (double)dk) * (1.0 / 147072.0)
                 - 2.0 * ((double)sxy - (double)csum) * (1.0 / 147456.0);
        out[k * 201] = (float)U;
    }
}

// ============ stage 3: per-(perm, kernel) gathered sums + final U_b ============
// 800 blocks (was 200 at 0.78/CU): block-count-over-efficiency lesson (R2/R8)
__global__ __launch_bounds__(256) void k_s3(const int* __restrict__ perms,
                                            const float* __restrict__ ws,
                                            float* __restrict__ out) {
    __shared__ float smem[32];
    int p = blockIdx.x, k = blockIdx.y, tid = threadIdx.x;
    int wave = tid >> 6, lane = tid & 63;
    const unsigned short* STT = (const unsigned short*)(ws + OF_STT);
    const unsigned short* KH  = (const unsigned short*)(ws + OF_KH);
    float v[4] = {0.f, 0.f, 0.f, 0.f};  // rs, cs, pair, qc
    for (int i = tid; i < NHALF; i += 256) {
        int a  = perms[p * NTOT + i];
        int bY = perms[p * NTOT + NHALF + i];
        float si  = bf2f(STT[p * NTOT + i]);
        float si2 = bf2f(STT[p * NTOT + NHALF + i]);
        v[0] += ws[OF_ROWM + k * NTOT + a];
        v[1] += ws[OF_COLM + k * NTOT + a];
        float kv = bf2f(KH[k * K0SZ + a * NTOT + bY]);
        if (a < NHALF && bY == a + NHALF) kv = 0.f;
        v[2] += kv;
        v[3] += ws[OF_C + k * NHALF + i] * si * si2;
    }
#pragma unroll
    for (int off = 32; off > 0; off >>= 1)
#pragma unroll
        for (int j = 0; j < 4; ++j) v[j] += __shfl_down(v[j], off, 64);
    if (lane == 0)
#pragma unroll
        for (int j = 0; j < 4; ++j) smem[wave * 4 + j] = v[j];
    __syncthreads();
    if (tid == 0) {
        double rs   = (double)(smem[0] + smem[4] + smem[8]  + smem[12]);
        double cs   = (double)(smem[1] + smem[5] + smem[9]  + smem[13]);
        double pair = (double)(smem[2] + smem[6] + smem[10] + smem[14]);
        double qc   = (double)(smem[3] + smem[7] + smem[11] + smem[15]);
        double total_mod = (double)ws[OF_SCAL + k * 4 + 0];
        double dk        = (double)ws[OF_SCAL + k * 4 + 1];
        double q = -qc;
#pragma unroll
        for (int j = 0; j < NPART; ++j) q += (double)ws[OF_Q0P + (k * NPART + j) * PPAD + p];
        double sXX = q - 384.0 * dk;
        double sYY = total_mod - rs - cs + q - 384.0 * dk;
        double sXY = rs - q - pair;
        out[k * 201 + 1 + p] =
            (float)(sXX * (1.0 / 147072.0) + sYY * (1.0 / 147072.0) - 2.0 * sXY * (1.0 / 147456.0));
    }
}

extern "C" void kernel_launch(void* const* d_in, const int* in_sizes, int n_in,
                              void* d_out, int out_size, void* d_ws, size_t ws_size,
                              hipStream_t stream) {
    const float* X     = (const float*)d_in[0];
    const float* Y     = (const float*)d_in[1];
    const float* bw    = (const float*)d_in[2];
    const int*   perms = (const int*)d_in[3];
    float* ws  = (float*)d_ws;
    float* out = (float*)d_out;

    k_s1<<<NPER + NTILE * NTILE, 256, 0, stream>>>(X, Y, bw, perms, ws);
    k_s2<<<NB_GEMM + NKER, 256, 0, stream>>>(bw, ws, out);
    k_s3<<<dim3(NPER, NKER), 256, 0, stream>>>(perms, ws, out);
}